// Round 5
// baseline (387.163 us; speedup 1.0000x reference)
//
#include <hip/hip_runtime.h>
#include <math.h>

#define VOCAB   100000
#define EMBED   300
#define BATCH   32768
#define K_NEG   10
#define EPSV    1e-5f

#define KPAD      320        // K padded to multiple of 32 (bf16 MFMA K)
#define NPAD      384        // W2 rows padded to 3*128 N tiles
#define CV_STRIDE 304        // center_v bf16 row stride in shorts (608 B)
#define WC2_STRIDE 304       // padded classifier row (f32)
#define NDB ((BATCH / 16) * 6)   // 12288 score slots (2048 rowgroups x 6 j-groups)
#define NCB (BATCH / 8)          // 4096 ce slots

typedef __attribute__((ext_vector_type(8))) short  short8;
typedef __attribute__((ext_vector_type(4))) float  f32x4;

__device__ inline unsigned short f2b(float f) {
    union { float f; unsigned int i; } v; v.f = f;
    unsigned int r = v.i + 0x7FFFu + ((v.i >> 16) & 1u);   // RNE
    return (unsigned short)(r >> 16);
}
// stable softplus via native exp2/log
__device__ inline float softplus_fast(float x) {
    const float t = __builtin_amdgcn_exp2f(fabsf(x) * -1.44269504f);
    const float l = __builtin_amdgcn_logf(1.f + t) * 0.69314718f;
    return fmaxf(x, 0.f) + l;
}
__device__ inline void load_lds16(const void* g, void* l) {
    __builtin_amdgcn_global_load_lds(
        (const __attribute__((address_space(1))) unsigned int*)g,
        (__attribute__((address_space(3))) unsigned int*)l, 16, 0, 0);
}
__device__ inline float red64(float v) {
    #pragma unroll
    for (int m = 32; m; m >>= 1) v += __shfl_xor(v, m);
    return v;
}
__device__ inline float wave_red64(float v) {
    #pragma unroll
    for (int o = 32; o; o >>= 1) v += __shfl_down(v, o);
    return v;
}
__device__ inline float dpick(const f32x4& a, int dreg) {
    return (dreg & 2) ? ((dreg & 1) ? a[3] : a[2])
                      : ((dreg & 1) ? a[1] : a[0]);
}

// ---------------------------------------------------------------------------
// ww: merged weight preprocessing.
//  blocks [0,480): W2 = W_dec @ W_enc -> bf16 [NPAD][KPAD] zero-padded
//  blocks [480,709): bias2 / wc2 / bc2 (one wave per output)
// ---------------------------------------------------------------------------
__global__ __launch_bounds__(256)
void ww_kernel(const float* __restrict__ Wd, const float* __restrict__ We,
               const float* __restrict__ Wc, const float* __restrict__ b_enc,
               const float* __restrict__ b_dec, const float* __restrict__ b_cls,
               unsigned short* __restrict__ w2p, float* __restrict__ wc2,
               float* __restrict__ bias2, float* __restrict__ bc2)
{
    __shared__ float ds[16][33];
    __shared__ float es[32][17];
    const int b = blockIdx.x;
    if (b < 480) {
        const int tid = threadIdx.x;
        const int tn = tid >> 4, tk = tid & 15;
        const int bx = b % 20, by = b / 20;
        const int n = by * 16 + tn;
        const int k = bx * 16 + tk;

        float acc = 0.f;
        for (int h0 = 0; h0 < 300; h0 += 32) {
            {
                const int i = tid * 2;
                const int a = i >> 5, h = i & 31;
                const int rr = by * 16 + a;
                #pragma unroll
                for (int j = 0; j < 2; ++j) {
                    const int hh = h + j;
                    ds[a][hh] = (rr < 300 && h0 + hh < 300) ? Wd[rr * 300 + h0 + hh] : 0.f;
                }
            }
            {
                const int i = tid * 2;
                const int h = i >> 4, c = i & 15;
                const int cc = bx * 16 + c;
                #pragma unroll
                for (int j = 0; j < 2; ++j)
                    es[h][c + j] = (h0 + h < 300 && cc + j < 300) ? We[(h0 + h) * 300 + cc + j] : 0.f;
            }
            __syncthreads();
            #pragma unroll
            for (int h = 0; h < 32; ++h)
                acc = fmaf(ds[tn][h], es[h][tk], acc);
            __syncthreads();
        }
        w2p[n * KPAD + k] = (n < 300 && k < 300) ? f2b(acc) : (unsigned short)0;
    } else {
        const int unit = (b - 480) * 4 + (threadIdx.x >> 6);
        const int lane = threadIdx.x & 63;
        if (unit >= 914) return;
        float s = 0.f;
        if (unit < 304) {
            const int c = unit;
            if (c < 300)
                for (int k = lane; k < 300; k += 64) s = fmaf(Wd[c * 300 + k], b_enc[k], s);
            s = red64(s);
            if (lane == 0) bias2[c] = (c < 300) ? s + b_dec[c] : 0.f;
        } else if (unit < 912) {
            const int u2 = unit - 304;
            const int j = u2 >= 304 ? 1 : 0;
            const int c = u2 - j * 304;
            if (c < 300)
                for (int h = lane; h < 300; h += 64) s = fmaf(Wc[j * 300 + h], We[h * 300 + c], s);
            s = red64(s);
            if (lane == 0) wc2[j * WC2_STRIDE + c] = s;
        } else {
            const int j = unit - 912;
            for (int h = lane; h < 300; h += 64) s = fmaf(Wc[j * 300 + h], b_enc[h], s);
            s = red64(s);
            if (lane == 0) bc2[j] = s + b_cls[j];
        }
    }
}

// ---------------------------------------------------------------------------
// gemm_fused: A staged directly from cemb via cids (f32 -> f2b bf16, reg-stage,
// same pre-swizzled layout as the old prep+global_load_lds path -> identical
// LDS bytes). B via global_load_lds from w2p. Double-buffered, one barrier/iter.
// cv[m,n] = sum_k emb[m,k]*W2[n,k] + bias2[n]; out bf16, cols [300,304) zeroed.
// ---------------------------------------------------------------------------
__global__ __launch_bounds__(256)
void gemm_fused(const float* __restrict__ cemb, const int* __restrict__ cids,
                const unsigned short* __restrict__ B,
                const float* __restrict__ bias,
                unsigned short* __restrict__ C)
{
    __shared__ unsigned short As[2][128 * 32];
    __shared__ unsigned short Bs[2][128 * 32];

    const int tid  = threadIdx.x;
    const int wave = tid >> 6;
    const int lane = tid & 63;
    const int m0 = blockIdx.y * 128;
    const int n0 = blockIdx.x * 128;

    const int wr = (wave & 1) * 64;
    const int wc = (wave >> 1) * 64;
    const int fr = lane & 15;
    const int fq = lane >> 4;

    const float* gA[2];
    int abase[2];
    const unsigned short* gB[2];
    int ldsOff[2];
    #pragma unroll
    for (int inst = 0; inst < 2; ++inst) {
        const int t = wave * 2 + inst;
        const int r = (t << 4) + (lane >> 2);
        const int c = ((lane & 3) - r - (r >> 2)) & 3;
        gA[inst] = cemb + (size_t)cids[m0 + r] * 300 + c * 8;
        abase[inst] = c * 8;
        gB[inst] = B + (size_t)(n0 + r) * KPAD + c * 8;
        ldsOff[inst] = t << 9;
    }

    int aoff[4], boff[4];
    #pragma unroll
    for (int i = 0; i < 4; ++i) {
        const int ra = wr + i * 16 + fr;
        aoff[i] = (ra << 5) + (((fq + ra + (ra >> 2)) & 3) << 3);
        const int rb = wc + i * 16 + fr;
        boff[i] = (rb << 5) + (((fq + rb + (rb >> 2)) & 3) << 3);
    }

    f32x4 acc[4][4] = {};
    float4 a0[2], a1[2];
    const float4 FZ4 = make_float4(0.f, 0.f, 0.f, 0.f);

#define LOADA(ki_) do { \
    _Pragma("unroll") \
    for (int inst = 0; inst < 2; ++inst) { \
        const int base_ = (ki_) * 32 + abase[inst]; \
        if (base_ < 296) { \
            a0[inst] = *(const float4*)(gA[inst] + (ki_) * 32); \
            a1[inst] = *(const float4*)(gA[inst] + (ki_) * 32 + 4); \
        } else if (base_ == 296) { \
            a0[inst] = *(const float4*)(gA[inst] + (ki_) * 32); \
            a1[inst] = FZ4; \
        } else { a0[inst] = FZ4; a1[inst] = FZ4; } \
    } } while (0)

#define WRITEA(buf_) do { \
    _Pragma("unroll") \
    for (int inst = 0; inst < 2; ++inst) { \
        uint4 d_; \
        d_.x = (unsigned)f2b(a0[inst].x) | ((unsigned)f2b(a0[inst].y) << 16); \
        d_.y = (unsigned)f2b(a0[inst].z) | ((unsigned)f2b(a0[inst].w) << 16); \
        d_.z = (unsigned)f2b(a1[inst].x) | ((unsigned)f2b(a1[inst].y) << 16); \
        d_.w = (unsigned)f2b(a1[inst].z) | ((unsigned)f2b(a1[inst].w) << 16); \
        *(uint4*)&As[buf_][ldsOff[inst] + lane * 8] = d_; \
    } } while (0)

    // prologue: stage chunk 0
    LOADA(0);
    load_lds16(gB[0], &Bs[0][ldsOff[0]]);
    load_lds16(gB[1], &Bs[0][ldsOff[1]]);
    WRITEA(0);

    int cur = 0;
    for (int ki = 0; ki < KPAD / 32; ++ki) {
        __syncthreads();                 // As/Bs[cur] resident; prev reads done
        if (ki + 1 < KPAD / 32) {
            const int k0 = (ki + 1) * 32;
            load_lds16(gB[0] + k0, &Bs[cur ^ 1][ldsOff[0]]);
            load_lds16(gB[1] + k0, &Bs[cur ^ 1][ldsOff[1]]);
            LOADA(ki + 1);               // issue gather loads early
        }
        short8 af[4], bf[4];
        #pragma unroll
        for (int i = 0; i < 4; ++i) af[i] = *(const short8*)&As[cur][aoff[i]];
        #pragma unroll
        for (int j = 0; j < 4; ++j) bf[j] = *(const short8*)&Bs[cur][boff[j]];
        #pragma unroll
        for (int i = 0; i < 4; ++i)
            #pragma unroll
            for (int j = 0; j < 4; ++j)
                acc[i][j] = __builtin_amdgcn_mfma_f32_16x16x32_bf16(
                    af[i], bf[j], acc[i][j], 0, 0, 0);
        if (ki + 1 < KPAD / 32) WRITEA(cur ^ 1);   // convert+write late
        cur ^= 1;
    }
#undef LOADA
#undef WRITEA

    #pragma unroll
    for (int i = 0; i < 4; ++i) {
        #pragma unroll
        for (int r = 0; r < 4; ++r) {
            const int m = m0 + wr + i * 16 + fq * 4 + r;
            unsigned short* crow = C + (size_t)m * CV_STRIDE;
            #pragma unroll
            for (int j = 0; j < 4; ++j) {
                const int n = n0 + wc + j * 16 + fr;
                if (n < 300) {
                    crow[n] = f2b(acc[i][j][r] + bias[n]);
                } else if (n < CV_STRIDE) {
                    crow[n] = 0;
                }
            }
        }
    }
}

// ---------------------------------------------------------------------------
// score (MFMA batched-diagonal, j-split x6): wave owns 16 rows x 2 ids.
// gidx = rowgroup*6 + jg; jg covers j = {2jg, 2jg+1} (j==0 is the positive).
// Dual interleaved MFMA streams; lane0 writes its slot (no atomics).
// ---------------------------------------------------------------------------
#define SCORE_BLOCKS (NDB / 4)

__global__ __launch_bounds__(256)
void score_kernel(const unsigned short* __restrict__ cvb,
                  const float* __restrict__ xemb,
                  const int* __restrict__ ctx_ids, const int* __restrict__ neg_ids,
                  float* __restrict__ db)
{
    const int wid  = threadIdx.x >> 6;
    const int lane = threadIdx.x & 63;
    const int fr = lane & 15;
    const int fq = lane >> 4;
    const int gidx = blockIdx.x * 4 + wid;
    const int rowgrp = gidx / 6;
    const int jg = gidx - rowgrp * 6;
    const int myrow = rowgrp * 16 + fr;

    union { uint4 u; short8 v; } z16; z16.u = make_uint4(0, 0, 0, 0);

    short8 af[10];
    const unsigned short* arow = cvb + (size_t)myrow * CV_STRIDE + fq * 8;
    #pragma unroll
    for (int kk = 0; kk < 10; ++kk) {
        if (kk < 9 || fq < 2) af[kk] = *(const short8*)(arow + kk * 32);
        else af[kk] = z16.v;
    }

    const int j0 = jg * 2;
    const bool has1 = (jg < 5);
    const int j1 = has1 ? j0 + 1 : 10;
    const int id0 = (j0 == 0) ? ctx_ids[myrow] : neg_ids[myrow * K_NEG + (j0 - 1)];
    const int id1 = neg_ids[myrow * K_NEG + (j1 - 1)];
    const float* b0 = xemb + (size_t)id0 * 300;
    const float* b1 = xemb + (size_t)id1 * 300;

    f32x4 acc0 = {}, acc1 = {};
    #pragma unroll
    for (int kk = 0; kk < 10; ++kk) {
        const int kb = kk * 32 + fq * 8;
        uint4 u0a, u0b, u1a, u1b;
        if (kk < 9 || fq == 0) {
            u0a = *(const uint4*)(b0 + kb); u0b = *(const uint4*)(b0 + kb + 4);
            u1a = *(const uint4*)(b1 + kb); u1b = *(const uint4*)(b1 + kb + 4);
        } else if (fq == 1) {
            u0a = *(const uint4*)(b0 + 296); u0b = make_uint4(0, 0, 0, 0);
            u1a = *(const uint4*)(b1 + 296); u1b = make_uint4(0, 0, 0, 0);
        } else {
            u0a = make_uint4(0, 0, 0, 0); u0b = u0a; u1a = u0a; u1b = u0a;
        }
        union { unsigned w[4]; short8 v; } bf0, bf1;
        bf0.w[0] = (u0a.y & 0xFFFF0000u) | (u0a.x >> 16);
        bf0.w[1] = (u0a.w & 0xFFFF0000u) | (u0a.z >> 16);
        bf0.w[2] = (u0b.y & 0xFFFF0000u) | (u0b.x >> 16);
        bf0.w[3] = (u0b.w & 0xFFFF0000u) | (u0b.z >> 16);
        bf1.w[0] = (u1a.y & 0xFFFF0000u) | (u1a.x >> 16);
        bf1.w[1] = (u1a.w & 0xFFFF0000u) | (u1a.z >> 16);
        bf1.w[2] = (u1b.y & 0xFFFF0000u) | (u1b.x >> 16);
        bf1.w[3] = (u1b.w & 0xFFFF0000u) | (u1b.z >> 16);
        acc0 = __builtin_amdgcn_mfma_f32_16x16x32_bf16(af[kk], bf0.v, acc0, 0, 0, 0);
        acc1 = __builtin_amdgcn_mfma_f32_16x16x32_bf16(af[kk], bf1.v, acc1, 0, 0, 0);
    }

    float loss = 0.f;
    const bool dlane = (fr >> 2) == fq;
    const int  dreg  = fr & 3;
    if (dlane) {
        float s0 = fminf(10.f, fmaxf(-10.f, dpick(acc0, dreg)));
        loss = softplus_fast(j0 == 0 ? -s0 : s0);
        if (has1) {
            float s1 = fminf(10.f, fmaxf(-10.f, dpick(acc1, dreg)));
            loss += softplus_fast(s1);
        }
    }
    float v = red64(loss);
    if (lane == 0) db[gidx] = v;
}

// ---------------------------------------------------------------------------
// CE (direct f32 gather): each wave = 2 rows in 32-lane halves;
// logits = cemb[cids[row]]·wc2[j] + bc2[j]. One slot-write per block.
// ---------------------------------------------------------------------------
__global__ __launch_bounds__(256)
void ce_kernel(const float* __restrict__ cemb, const int* __restrict__ cids,
               const int* __restrict__ labels,
               const float* __restrict__ wc2, const float* __restrict__ bc2,
               float* __restrict__ cb)
{
    __shared__ float s8[8];
    const int wid  = threadIdx.x >> 6;
    const int lane = threadIdx.x & 63;
    const int l5   = lane & 31;
    const int slot = wid * 2 + (lane >> 5);
    const int row  = blockIdx.x * 8 + slot;
    const bool act = l5 < 19;

    float p0 = 0.f, p1 = 0.f;
    if (act) {
        const float* src = cemb + (size_t)cids[row] * 300;
        const int e0 = l5 * 16;
        const float* w0 = wc2 + e0;
        const float* w1 = wc2 + WC2_STRIDE + e0;
        #pragma unroll
        for (int q = 0; q < 4; ++q) {
            const int e = e0 + q * 4;
            if (e + 3 < 300) {
                float4 v = *(const float4*)(src + e);
                float4 a = *(const float4*)(w0 + q * 4);
                float4 c = *(const float4*)(w1 + q * 4);
                p0 = fmaf(v.x, a.x, p0); p0 = fmaf(v.y, a.y, p0);
                p0 = fmaf(v.z, a.z, p0); p0 = fmaf(v.w, a.w, p0);
                p1 = fmaf(v.x, c.x, p1); p1 = fmaf(v.y, c.y, p1);
                p1 = fmaf(v.z, c.z, p1); p1 = fmaf(v.w, c.w, p1);
            }
        }
    }
    #pragma unroll
    for (int m = 16; m; m >>= 1) { p0 += __shfl_xor(p0, m); p1 += __shfl_xor(p1, m); }

    if (l5 == 0) {
        const float l0 = p0 + bc2[0];
        const float l1 = p1 + bc2[1];
        const float mx = fmaxf(l0, l1);
        const float lse = mx + logf(expf(l0 - mx) + expf(l1 - mx));
        s8[slot] = lse - (labels[row] ? l1 : l0);
    }
    __syncthreads();
    if (threadIdx.x == 0) {
        cb[blockIdx.x] = s8[0] + s8[1] + s8[2] + s8[3] + s8[4] + s8[5] + s8[6] + s8[7];
    }
}

// ---------------------------------------------------------------------------
__global__ __launch_bounds__(256)
void finalize_kernel(const float* __restrict__ db, const float* __restrict__ cb,
                     float* __restrict__ out)
{
    const int t = threadIdx.x;
    float d = 0.f, c = 0.f;
    for (int i = t; i < NDB; i += 256) d += db[i];
    for (int i = t; i < NCB; i += 256) c += cb[i];
    d = wave_red64(d); c = wave_red64(c);
    __shared__ float sd[4], sc[4];
    if ((t & 63) == 0) { sd[t >> 6] = d; sc[t >> 6] = c; }
    __syncthreads();
    if (t == 0) {
        const float inv = 1.0f / (float)BATCH;
        float deno = (sd[0] + sd[1] + sd[2] + sd[3]) * inv;
        float cono = (sc[0] + sc[1] + sc[2] + sc[3]) * inv;
        deno = fminf(10.f, fmaxf(EPSV, deno));
        cono = fminf(10.f, fmaxf(EPSV, cono));
        out[0] = fmaxf(EPSV, deno + cono);
        out[1] = deno;
        out[2] = cono;
    }
}

extern "C" void kernel_launch(void* const* d_in, const int* in_sizes, int n_in,
                              void* d_out, int out_size, void* d_ws, size_t ws_size,
                              hipStream_t stream)
{
    const int*   cids  = (const int*)d_in[0];
    const int*   ctx   = (const int*)d_in[1];
    const int*   neg   = (const int*)d_in[2];
    const int*   lab   = (const int*)d_in[3];
    const float* cemb  = (const float*)d_in[4];
    const float* xemb  = (const float*)d_in[5];
    const float* W_enc = (const float*)d_in[6];
    const float* b_enc = (const float*)d_in[7];
    const float* W_dec = (const float*)d_in[8];
    const float* b_dec = (const float*)d_in[9];
    const float* W_cls = (const float*)d_in[10];
    const float* b_cls = (const float*)d_in[11];
    float* out = (float*)d_out;

    // workspace (~20.3 MB, all 16B aligned)
    unsigned short* cv_b = (unsigned short*)d_ws;                    // [BATCH][CV_STRIDE]
    unsigned short* w2p  = cv_b + (size_t)BATCH * CV_STRIDE;         // [NPAD][KPAD]
    float* wc2   = (float*)(w2p + (size_t)NPAD * KPAD);              // [2][WC2_STRIDE]
    float* bias2 = wc2 + 2 * WC2_STRIDE;                             // [WC2_STRIDE]
    float* bc2   = bias2 + WC2_STRIDE;                               // [2] (+pad)
    float* db    = bc2 + 4;                                          // [NDB]
    float* cb    = db + NDB;                                         // [NCB]

    ww_kernel<<<709, 256, 0, stream>>>(W_dec, W_enc, W_cls, b_enc, b_dec, b_cls,
                                       w2p, wc2, bias2, bc2);

    dim3 ggrid(3, BATCH / 128);
    gemm_fused<<<ggrid, 256, 0, stream>>>(cemb, cids, w2p, bias2, cv_b);

    score_kernel<<<SCORE_BLOCKS, 256, 0, stream>>>(cv_b, xemb, ctx, neg, db);
    ce_kernel<<<BATCH / 8, 256, 0, stream>>>(cemb, cids, lab, wc2, bc2, cb);

    finalize_kernel<<<1, 256, 0, stream>>>(db, cb, out);
}